// Round 1
// baseline (2898.429 us; speedup 1.0000x reference)
//
#include <hip/hip_runtime.h>
#include <math.h>

// Problem constants: B=8, CIN=3, COUT=16, H=W=384
#define BQ   8
#define CIN  3
#define COUT 16
#define HW   (384 * 384)            // 147456
#define NPIX (BQ * HW)              // 1,179,648 pixels
#define NELT 18874368.0f            // NPIX * COUT
#define MAX_ITERS 16

#define TPB       256
#define BPC       6                 // blocks per CU; launch_bounds(256,6) => 6 waves/EU
#define NBLK      (BPC * 256)       // 1536 blocks, co-resident by construction
#define NTHREADS  (NBLK * TPB)      // 393,216
#define PPT       3                 // 393,216 * 3 == NPIX exactly; 48 state floats/thread

#define NLEAF        64
#define BLK_PER_LEAF (NBLK / NLEAF) // 24

typedef float vfloat16 __attribute__((ext_vector_type(16)));

struct __align__(64) PadCnt { int cnt; int pad[15]; };  // one cache line each

struct Ctl {
    PadCnt leaf[NLEAF];                 // barrier leaf counters (24-way fan-in)
    PadCnt root;                        // barrier root counter (64-way fan-in)
    PadCnt sense;                       // barrier sense (read-only spin target)
    float  partials[2][NBLK];           // ping-pong per-block |v| partial sums
                                        // (slot reuse ordered by the grid barrier)
};

__global__ void k_init(Ctl* c) {
    int t = threadIdx.x;
    if (t < NLEAF) c->leaf[t].cnt = 0;
    if (t == 0) { c->root.cnt = 0; c->sense.cnt = 0; }
}

// tanh(x) = 1 - 2/(exp(2x)+1): v_exp_f32 + v_rcp_f32, ~6 instrs, ~1e-7 abs err.
__device__ __forceinline__ float tanh_fast(float x) {
    float e = __expf(2.0f * x);
    return fmaf(-2.0f, __builtin_amdgcn_rcpf(e + 1.0f), 1.0f);
}

// block = 256 threads = 4 waves; full block sum returned on tid 0
__device__ __forceinline__ float block_reduce_add(float v) {
    #pragma unroll
    for (int off = 32; off > 0; off >>= 1)
        v += __shfl_down(v, off, 64);
    __shared__ float red[TPB / 64];
    int lane = threadIdx.x & 63;
    int wid  = threadIdx.x >> 6;
    if (lane == 0) red[wid] = v;
    __syncthreads();
    float r = 0.f;
    if (threadIdx.x == 0) {
        #pragma unroll
        for (int i = 0; i < TPB / 64; ++i) r += red[i];
    }
    return r;
}

// Two-level sense-reversing grid barrier: leaf fan-in 24, root fan-in 64.
// All NBLK blocks co-resident by construction (grid == capacity).
__device__ __forceinline__ void grid_barrier(Ctl* c, int* sense_sh) {
    __syncthreads();
    if (threadIdx.x == 0) {
        int next = *sense_sh ^ 1;
        int lf = blockIdx.x & (NLEAF - 1);
        int p = __hip_atomic_fetch_add(&c->leaf[lf].cnt, 1, __ATOMIC_ACQ_REL,
                                       __HIP_MEMORY_SCOPE_AGENT);
        if (p == BLK_PER_LEAF - 1) {
            __hip_atomic_store(&c->leaf[lf].cnt, 0, __ATOMIC_RELAXED,
                               __HIP_MEMORY_SCOPE_AGENT);
            int q = __hip_atomic_fetch_add(&c->root.cnt, 1, __ATOMIC_ACQ_REL,
                                           __HIP_MEMORY_SCOPE_AGENT);
            if (q == NLEAF - 1) {
                __hip_atomic_store(&c->root.cnt, 0, __ATOMIC_RELAXED,
                                   __HIP_MEMORY_SCOPE_AGENT);
                __hip_atomic_store(&c->sense.cnt, next, __ATOMIC_RELEASE,
                                   __HIP_MEMORY_SCOPE_AGENT);
            }
        }
        while (__hip_atomic_load(&c->sense.cnt, __ATOMIC_ACQUIRE,
                                 __HIP_MEMORY_SCOPE_AGENT) != next)
            __builtin_amdgcn_s_sleep(4);
        *sense_sh = next;
    }
    __syncthreads();
}

// Deterministic grid sum: wave 0 sums all NBLK partials in a fixed order
// (identical in every block -> bitwise-identical -> uniform decision),
// broadcasts via LDS. Atomic relaxed agent loads dodge stale non-coherent L2.
__device__ __forceinline__ float grid_sum(const float* part, float* bc) {
    int lane = threadIdx.x & 63, wid = threadIdx.x >> 6;
    if (wid == 0) {
        float s = 0.f;
        #pragma unroll
        for (int i = 0; i < NBLK / 64; ++i)
            s += __hip_atomic_load(&part[i * 64 + lane], __ATOMIC_RELAXED,
                                   __HIP_MEMORY_SCOPE_AGENT);
        #pragma unroll
        for (int off = 32; off > 0; off >>= 1)
            s += __shfl_down(s, off, 64);
        if (lane == 0) *bc = s;
    }
    __syncthreads();
    return *bc;
}

#define PRE_PIXEL(vk, kk)                                                \
    { int p = tid + (kk) * NTHREADS; int b = p / HW; int hw = p - b * HW;\
      const float* xb = x + (size_t)b * (CIN * HW) + hw;                 \
      float x0 = xb[0], x1 = xb[HW], x2 = xb[2 * HW];                    \
      _Pragma("unroll")                                                  \
      for (int o = 0; o < COUT; ++o) {                                   \
          float a = bp[o];                                               \
          a = fmaf(wp[o * CIN + 0], x0, a);                              \
          a = fmaf(wp[o * CIN + 1], x1, a);                              \
          a = fmaf(wp[o * CIN + 2], x2, a);                              \
          vk[o] = a; s += fabsf(a);                                      \
      } }

__global__ __launch_bounds__(TPB, BPC) void k_persist(
        const float* __restrict__ x,
        const float* __restrict__ wp, const float* __restrict__ bp,
        const float* __restrict__ wl, const float* __restrict__ bl,
        const float* __restrict__ ws, const float* __restrict__ bs,
        float* __restrict__ out, Ctl* __restrict__ ctl) {
    __shared__ int sense_sh;
    __shared__ float bcast;
    const int t = threadIdx.x;
    if (t == 0) sense_sh = 0;
    __syncthreads();

    const int tid = blockIdx.x * TPB + t;

    // State: 3 named 16-wide vectors = 48 registers. No runtime indexing.
    vfloat16 v0, v1, v2;

    // ---- pre conv + |v| partial
    float s = 0.f;
    PRE_PIXEL(v0, 0) PRE_PIXEL(v1, 1) PRE_PIXEL(v2, 2)
    {
        float r = block_reduce_add(s);
        if (t == 0)
            __hip_atomic_store(&ctl->partials[0][blockIdx.x], r,
                               __ATOMIC_RELAXED, __HIP_MEMORY_SCOPE_AGENT);
    }
    grid_barrier(ctl, &sense_sh);

    // ---- while (mean|v| < 3): v = 10*(wl @ tanh(ws @ v + bs) + bl)
    // 3 pixels processed jointly: each scalar weight load feeds 3 independent
    // FMA chains (ILP + 3x SMEM amortization).
    int it = 0;
    while (it < MAX_ITERS) {
        float total = grid_sum(ctl->partials[it & 1], &bcast);
        if (total >= 3.0f * NELT) break;      // uniform across all blocks

        s = 0.f;
        {
            float t0[COUT], t1[COUT], t2[COUT];
            #pragma unroll
            for (int o = 0; o < COUT; ++o) {
                float a0 = bs[o], a1 = bs[o], a2 = bs[o];
                #pragma unroll
                for (int c = 0; c < COUT; ++c) {
                    float w = ws[o * COUT + c];
                    a0 = fmaf(w, v0[c], a0);
                    a1 = fmaf(w, v1[c], a1);
                    a2 = fmaf(w, v2[c], a2);
                }
                t0[o] = tanh_fast(a0);
                t1[o] = tanh_fast(a1);
                t2[o] = tanh_fast(a2);
            }
            #pragma unroll
            for (int o = 0; o < COUT; ++o) {
                float a0 = bl[o], a1 = bl[o], a2 = bl[o];
                #pragma unroll
                for (int c = 0; c < COUT; ++c) {
                    float w = wl[o * COUT + c];
                    a0 = fmaf(w, t0[c], a0);
                    a1 = fmaf(w, t1[c], a1);
                    a2 = fmaf(w, t2[c], a2);
                }
                a0 *= 10.f; a1 *= 10.f; a2 *= 10.f;
                v0[o] = a0; v1[o] = a1; v2[o] = a2;
                s += fabsf(a0) + fabsf(a1) + fabsf(a2);
            }
        }
        ++it;
        float r = block_reduce_add(s);
        if (t == 0)
            __hip_atomic_store(&ctl->partials[it & 1][blockIdx.x], r,
                               __ATOMIC_RELAXED, __HIP_MEMORY_SCOPE_AGENT);
        grid_barrier(ctl, &sense_sh);
    }

    // ---- final conv, 3 pixels jointly (weight reuse)
    {
        int p0 = tid,                 b0 = p0 / HW, hw0 = p0 - b0 * HW;
        int p1 = tid + NTHREADS,      b1 = p1 / HW, hw1 = p1 - b1 * HW;
        int p2 = tid + 2 * NTHREADS,  b2 = p2 / HW, hw2 = p2 - b2 * HW;
        float* ob0 = out + (size_t)b0 * (COUT * HW) + hw0;
        float* ob1 = out + (size_t)b1 * (COUT * HW) + hw1;
        float* ob2 = out + (size_t)b2 * (COUT * HW) + hw2;
        #pragma unroll
        for (int o = 0; o < COUT; ++o) {
            float a0 = bs[o], a1 = bs[o], a2 = bs[o];
            #pragma unroll
            for (int c = 0; c < COUT; ++c) {
                float w = ws[o * COUT + c];
                a0 = fmaf(w, v0[c], a0);
                a1 = fmaf(w, v1[c], a1);
                a2 = fmaf(w, v2[c], a2);
            }
            ob0[(size_t)o * HW] = a0;
            ob1[(size_t)o * HW] = a1;
            ob2[(size_t)o * HW] = a2;
        }
    }
}

extern "C" void kernel_launch(void* const* d_in, const int* in_sizes, int n_in,
                              void* d_out, int out_size, void* d_ws, size_t ws_size,
                              hipStream_t stream) {
    // dict order: x, w_pre, b_pre, w_loop, b_loop, w_shared, b_shared
    const float* x  = (const float*)d_in[0];
    const float* wp = (const float*)d_in[1];
    const float* bp = (const float*)d_in[2];
    const float* wl = (const float*)d_in[3];
    const float* bl = (const float*)d_in[4];
    const float* ws = (const float*)d_in[5];
    const float* bs = (const float*)d_in[6];
    float* out = (float*)d_out;
    Ctl*   ctl = (Ctl*)d_ws;

    k_init<<<1, 64, 0, stream>>>(ctl);
    k_persist<<<NBLK, TPB, 0, stream>>>(x, wp, bp, wl, bl, ws, bs, out, ctl);
}

// Round 2
// 705.212 us; speedup vs baseline: 4.1100x; 4.1100x over previous
//
#include <hip/hip_runtime.h>
#include <math.h>

// Problem constants: B=8, CIN=3, COUT=16, H=W=384
#define BQ   8
#define CIN  3
#define COUT 16
#define HW   (384 * 384)            // 147456
#define NPIX (BQ * HW)              // 1,179,648 pixels
#define NELT 18874368.0f            // NPIX * COUT
#define MAX_ITERS 16

#define TPB       256
#define BPC       3                 // 3 blocks/CU => 3 waves/EU => VGPR budget ~168/wave
#define NBLK      (BPC * 256)       // 768 blocks, co-resident by construction
#define NTHREADS  (NBLK * TPB)      // 196,608
#define PPT       6                 // 196,608 * 6 == NPIX exactly; 96 state floats/thread

#define NLEAF        64
#define BLK_PER_LEAF (NBLK / NLEAF) // 12

typedef float vfloat16 __attribute__((ext_vector_type(16)));

struct __align__(64) PadCnt { int cnt; int pad[15]; };  // one cache line each

struct Ctl {
    PadCnt leaf[NLEAF];                 // barrier leaf counters (12-way fan-in)
    PadCnt root;                        // barrier root counter (64-way fan-in)
    PadCnt sense;                       // barrier sense (read-only spin target)
    float  partials[2][NBLK];           // ping-pong per-block |v| partial sums
                                        // (slot reuse ordered by the grid barrier)
};

__global__ void k_init(Ctl* c) {
    int t = threadIdx.x;
    if (t < NLEAF) c->leaf[t].cnt = 0;
    if (t == 0) { c->root.cnt = 0; c->sense.cnt = 0; }
}

// tanh(x) = 1 - 2/(exp(2x)+1): v_exp_f32 + v_rcp_f32, ~6 instrs, ~1e-7 abs err.
__device__ __forceinline__ float tanh_fast(float x) {
    float e = __expf(2.0f * x);
    return fmaf(-2.0f, __builtin_amdgcn_rcpf(e + 1.0f), 1.0f);
}

// block = 256 threads = 4 waves; full block sum returned on tid 0
__device__ __forceinline__ float block_reduce_add(float v) {
    #pragma unroll
    for (int off = 32; off > 0; off >>= 1)
        v += __shfl_down(v, off, 64);
    __shared__ float red[TPB / 64];
    int lane = threadIdx.x & 63;
    int wid  = threadIdx.x >> 6;
    if (lane == 0) red[wid] = v;
    __syncthreads();
    float r = 0.f;
    if (threadIdx.x == 0) {
        #pragma unroll
        for (int i = 0; i < TPB / 64; ++i) r += red[i];
    }
    return r;
}

// Two-level sense-reversing grid barrier: leaf fan-in 12, root fan-in 64.
// All NBLK blocks co-resident by construction (grid == capacity at 3 blocks/CU).
__device__ __forceinline__ void grid_barrier(Ctl* c, int* sense_sh) {
    __syncthreads();
    if (threadIdx.x == 0) {
        int next = *sense_sh ^ 1;
        int lf = blockIdx.x & (NLEAF - 1);
        int p = __hip_atomic_fetch_add(&c->leaf[lf].cnt, 1, __ATOMIC_ACQ_REL,
                                       __HIP_MEMORY_SCOPE_AGENT);
        if (p == BLK_PER_LEAF - 1) {
            __hip_atomic_store(&c->leaf[lf].cnt, 0, __ATOMIC_RELAXED,
                               __HIP_MEMORY_SCOPE_AGENT);
            int q = __hip_atomic_fetch_add(&c->root.cnt, 1, __ATOMIC_ACQ_REL,
                                           __HIP_MEMORY_SCOPE_AGENT);
            if (q == NLEAF - 1) {
                __hip_atomic_store(&c->root.cnt, 0, __ATOMIC_RELAXED,
                                   __HIP_MEMORY_SCOPE_AGENT);
                __hip_atomic_store(&c->sense.cnt, next, __ATOMIC_RELEASE,
                                   __HIP_MEMORY_SCOPE_AGENT);
            }
        }
        while (__hip_atomic_load(&c->sense.cnt, __ATOMIC_ACQUIRE,
                                 __HIP_MEMORY_SCOPE_AGENT) != next)
            __builtin_amdgcn_s_sleep(4);
        *sense_sh = next;
    }
    __syncthreads();
}

// Deterministic grid sum: wave 0 sums all NBLK partials in a fixed order
// (identical in every block -> bitwise-identical -> uniform decision),
// broadcasts via LDS. Atomic relaxed agent loads dodge stale non-coherent L2.
__device__ __forceinline__ float grid_sum(const float* part, float* bc) {
    int lane = threadIdx.x & 63, wid = threadIdx.x >> 6;
    if (wid == 0) {
        float s = 0.f;
        #pragma unroll
        for (int i = 0; i < NBLK / 64; ++i)
            s += __hip_atomic_load(&part[i * 64 + lane], __ATOMIC_RELAXED,
                                   __HIP_MEMORY_SCOPE_AGENT);
        #pragma unroll
        for (int off = 32; off > 0; off >>= 1)
            s += __shfl_down(s, off, 64);
        if (lane == 0) *bc = s;
    }
    __syncthreads();
    return *bc;
}

#define PRE_PIXEL(vk, kk)                                                \
    { int p = tid + (kk) * NTHREADS; int b = p / HW; int hw = p - b * HW;\
      const float* xb = x + (size_t)b * (CIN * HW) + hw;                 \
      float x0 = xb[0], x1 = xb[HW], x2 = xb[2 * HW];                    \
      _Pragma("unroll")                                                  \
      for (int o = 0; o < COUT; ++o) {                                   \
          float a = bp[o];                                               \
          a = fmaf(wp[o * CIN + 0], x0, a);                              \
          a = fmaf(wp[o * CIN + 1], x1, a);                              \
          a = fmaf(wp[o * CIN + 2], x2, a);                              \
          vk[o] = a; s += fabsf(a);                                      \
      } }

// One loop-body step for a PAIR of pixels. Peak live: 96 state + 32 temps
// + working < 168 VGPR budget (no spill); each weight load feeds 2 chains.
#define STEP_PAIR(va, vb)                                                \
    { float ua[COUT], ub[COUT];                                          \
      _Pragma("unroll")                                                  \
      for (int o = 0; o < COUT; ++o) {                                   \
          float a0 = bs[o], a1 = bs[o];                                  \
          _Pragma("unroll")                                              \
          for (int c = 0; c < COUT; ++c) {                               \
              float w = ws[o * COUT + c];                                \
              a0 = fmaf(w, va[c], a0);                                   \
              a1 = fmaf(w, vb[c], a1);                                   \
          }                                                              \
          ua[o] = tanh_fast(a0); ub[o] = tanh_fast(a1);                  \
      }                                                                  \
      _Pragma("unroll")                                                  \
      for (int o = 0; o < COUT; ++o) {                                   \
          float a0 = bl[o], a1 = bl[o];                                  \
          _Pragma("unroll")                                              \
          for (int c = 0; c < COUT; ++c) {                               \
              float w = wl[o * COUT + c];                                \
              a0 = fmaf(w, ua[c], a0);                                   \
              a1 = fmaf(w, ub[c], a1);                                   \
          }                                                              \
          a0 *= 10.f; a1 *= 10.f;                                        \
          va[o] = a0; vb[o] = a1;                                        \
          s += fabsf(a0) + fabsf(a1);                                    \
      } }

#define FIN_PIXEL(vk, kk)                                                \
    { int p = tid + (kk) * NTHREADS; int b = p / HW; int hw = p - b * HW;\
      float* ob = out + (size_t)b * (COUT * HW) + hw;                    \
      _Pragma("unroll")                                                  \
      for (int o = 0; o < COUT; ++o) {                                   \
          float a = bs[o];                                               \
          _Pragma("unroll")                                              \
          for (int c = 0; c < COUT; ++c)                                 \
              a = fmaf(ws[o * COUT + c], vk[c], a);                      \
          ob[(size_t)o * HW] = a;                                        \
      } }

__global__ __launch_bounds__(TPB, BPC) void k_persist(
        const float* __restrict__ x,
        const float* __restrict__ wp, const float* __restrict__ bp,
        const float* __restrict__ wl, const float* __restrict__ bl,
        const float* __restrict__ ws, const float* __restrict__ bs,
        float* __restrict__ out, Ctl* __restrict__ ctl) {
    __shared__ int sense_sh;
    __shared__ float bcast;
    const int t = threadIdx.x;
    if (t == 0) sense_sh = 0;
    __syncthreads();

    const int tid = blockIdx.x * TPB + t;

    // State: 6 named 16-wide vectors = 96 registers. No runtime indexing.
    vfloat16 v0, v1, v2, v3, v4, v5;

    // ---- pre conv + |v| partial
    float s = 0.f;
    PRE_PIXEL(v0, 0) PRE_PIXEL(v1, 1) PRE_PIXEL(v2, 2)
    PRE_PIXEL(v3, 3) PRE_PIXEL(v4, 4) PRE_PIXEL(v5, 5)
    {
        float r = block_reduce_add(s);
        if (t == 0)
            __hip_atomic_store(&ctl->partials[0][blockIdx.x], r,
                               __ATOMIC_RELAXED, __HIP_MEMORY_SCOPE_AGENT);
    }
    grid_barrier(ctl, &sense_sh);

    // ---- while (mean|v| < 3): v = 10*(wl @ tanh(ws @ v + bs) + bl)
    int it = 0;
    while (it < MAX_ITERS) {
        float total = grid_sum(ctl->partials[it & 1], &bcast);
        if (total >= 3.0f * NELT) break;      // uniform across all blocks

        s = 0.f;
        STEP_PAIR(v0, v1)
        STEP_PAIR(v2, v3)
        STEP_PAIR(v4, v5)
        ++it;
        float r = block_reduce_add(s);
        if (t == 0)
            __hip_atomic_store(&ctl->partials[it & 1][blockIdx.x], r,
                               __ATOMIC_RELAXED, __HIP_MEMORY_SCOPE_AGENT);
        grid_barrier(ctl, &sense_sh);
    }

    // ---- final conv (per pixel; write-BW bound, weights K$-resident)
    FIN_PIXEL(v0, 0) FIN_PIXEL(v1, 1) FIN_PIXEL(v2, 2)
    FIN_PIXEL(v3, 3) FIN_PIXEL(v4, 4) FIN_PIXEL(v5, 5)
}

extern "C" void kernel_launch(void* const* d_in, const int* in_sizes, int n_in,
                              void* d_out, int out_size, void* d_ws, size_t ws_size,
                              hipStream_t stream) {
    // dict order: x, w_pre, b_pre, w_loop, b_loop, w_shared, b_shared
    const float* x  = (const float*)d_in[0];
    const float* wp = (const float*)d_in[1];
    const float* bp = (const float*)d_in[2];
    const float* wl = (const float*)d_in[3];
    const float* bl = (const float*)d_in[4];
    const float* ws = (const float*)d_in[5];
    const float* bs = (const float*)d_in[6];
    float* out = (float*)d_out;
    Ctl*   ctl = (Ctl*)d_ws;

    k_init<<<1, 64, 0, stream>>>(ctl);
    k_persist<<<NBLK, TPB, 0, stream>>>(x, wp, bp, wl, bl, ws, bs, out, ctl);
}

// Round 3
// 437.787 us; speedup vs baseline: 6.6206x; 1.6109x over previous
//
#include <hip/hip_runtime.h>
#include <math.h>

// Problem constants: B=8, CIN=3, COUT=16, H=W=384
#define BQ   8
#define CIN  3
#define COUT 16
#define HW   (384 * 384)            // 147456
#define NPIX (BQ * HW)              // 1,179,648 pixels
#define NELT 18874368.0f            // NPIX * COUT
#define MAX_ITERS 16

#define TPB       256
#define BPC       2                 // 2 blocks/CU: the PROVEN zero-spill budget (256 reg/wave)
#define NBLK      (BPC * 256)       // 512 blocks, co-resident by construction
#define NTHREADS  (NBLK * TPB)      // 131,072
#define PPT       9                 // 131,072 * 9 == NPIX exactly; 144 state floats/thread

#define NLEAF        64
#define BLK_PER_LEAF (NBLK / NLEAF) // 8

typedef float vfloat16 __attribute__((ext_vector_type(16)));

struct __align__(64) PadCnt { int cnt; int pad[15]; };  // one cache line each

struct Ctl {
    PadCnt leaf[NLEAF];                 // barrier leaf counters (8-way fan-in)
    PadCnt root;                        // barrier root counter (64-way fan-in)
    PadCnt sense;                       // barrier sense (read-only spin target)
    float  partials[2][NBLK];           // ping-pong per-block |v| partial sums
                                        // (slot reuse ordered by the grid barrier)
};

__global__ void k_init(Ctl* c) {
    int t = threadIdx.x;
    if (t < NLEAF) c->leaf[t].cnt = 0;
    if (t == 0) { c->root.cnt = 0; c->sense.cnt = 0; }
}

// tanh(x) = 1 - 2/(exp(2x)+1): v_exp_f32 + v_rcp_f32, ~6 instrs, ~1e-7 abs err.
__device__ __forceinline__ float tanh_fast(float x) {
    float e = __expf(2.0f * x);
    return fmaf(-2.0f, __builtin_amdgcn_rcpf(e + 1.0f), 1.0f);
}

// block = 256 threads = 4 waves; full block sum returned on tid 0
__device__ __forceinline__ float block_reduce_add(float v) {
    #pragma unroll
    for (int off = 32; off > 0; off >>= 1)
        v += __shfl_down(v, off, 64);
    __shared__ float red[TPB / 64];
    int lane = threadIdx.x & 63;
    int wid  = threadIdx.x >> 6;
    if (lane == 0) red[wid] = v;
    __syncthreads();
    float r = 0.f;
    if (threadIdx.x == 0) {
        #pragma unroll
        for (int i = 0; i < TPB / 64; ++i) r += red[i];
    }
    return r;
}

// Two-level sense-reversing grid barrier: leaf fan-in 8, root fan-in 64.
// All NBLK blocks co-resident by construction (grid == capacity at 2 blocks/CU).
__device__ __forceinline__ void grid_barrier(Ctl* c, int* sense_sh) {
    __syncthreads();
    if (threadIdx.x == 0) {
        int next = *sense_sh ^ 1;
        int lf = blockIdx.x & (NLEAF - 1);
        int p = __hip_atomic_fetch_add(&c->leaf[lf].cnt, 1, __ATOMIC_ACQ_REL,
                                       __HIP_MEMORY_SCOPE_AGENT);
        if (p == BLK_PER_LEAF - 1) {
            __hip_atomic_store(&c->leaf[lf].cnt, 0, __ATOMIC_RELAXED,
                               __HIP_MEMORY_SCOPE_AGENT);
            int q = __hip_atomic_fetch_add(&c->root.cnt, 1, __ATOMIC_ACQ_REL,
                                           __HIP_MEMORY_SCOPE_AGENT);
            if (q == NLEAF - 1) {
                __hip_atomic_store(&c->root.cnt, 0, __ATOMIC_RELAXED,
                                   __HIP_MEMORY_SCOPE_AGENT);
                __hip_atomic_store(&c->sense.cnt, next, __ATOMIC_RELEASE,
                                   __HIP_MEMORY_SCOPE_AGENT);
            }
        }
        while (__hip_atomic_load(&c->sense.cnt, __ATOMIC_ACQUIRE,
                                 __HIP_MEMORY_SCOPE_AGENT) != next)
            __builtin_amdgcn_s_sleep(4);
        *sense_sh = next;
    }
    __syncthreads();
}

// Deterministic grid sum: wave 0 sums all NBLK partials in a fixed order
// (identical in every block -> bitwise-identical -> uniform decision),
// broadcasts via LDS. Atomic relaxed agent loads dodge stale non-coherent L2.
__device__ __forceinline__ float grid_sum(const float* part, float* bc) {
    int lane = threadIdx.x & 63, wid = threadIdx.x >> 6;
    if (wid == 0) {
        float s = 0.f;
        #pragma unroll
        for (int i = 0; i < NBLK / 64; ++i)
            s += __hip_atomic_load(&part[i * 64 + lane], __ATOMIC_RELAXED,
                                   __HIP_MEMORY_SCOPE_AGENT);
        #pragma unroll
        for (int off = 32; off > 0; off >>= 1)
            s += __shfl_down(s, off, 64);
        if (lane == 0) *bc = s;
    }
    __syncthreads();
    return *bc;
}

#define PRE_PIXEL(vk, kk)                                                \
    { int p = tid + (kk) * NTHREADS; int b = p / HW; int hw = p - b * HW;\
      const float* xb = x + (size_t)b * (CIN * HW) + hw;                 \
      float x0 = xb[0], x1 = xb[HW], x2 = xb[2 * HW];                    \
      _Pragma("unroll")                                                  \
      for (int o = 0; o < COUT; ++o) {                                   \
          float a = bp[o];                                               \
          a = fmaf(wp[o * CIN + 0], x0, a);                              \
          a = fmaf(wp[o * CIN + 1], x1, a);                              \
          a = fmaf(wp[o * CIN + 2], x2, a);                              \
          vk[o] = a; s += fabsf(a);                                      \
      } }

// One loop-body step for a TRIPLE of pixels: each scalar weight load feeds
// 3 independent FMA chains (3x ILP, 3x fewer SMEM weight passes).
// Peak live: 144 state + 48 temps + working ~= 208 < 256-reg proven budget.
#define STEP_TRIPLE(va, vb, vc)                                          \
    { float ua[COUT], ub[COUT], uc[COUT];                                \
      _Pragma("unroll")                                                  \
      for (int o = 0; o < COUT; ++o) {                                   \
          float a0 = bs[o], a1 = bs[o], a2 = bs[o];                      \
          _Pragma("unroll")                                              \
          for (int c = 0; c < COUT; ++c) {                               \
              float w = ws[o * COUT + c];                                \
              a0 = fmaf(w, va[c], a0);                                   \
              a1 = fmaf(w, vb[c], a1);                                   \
              a2 = fmaf(w, vc[c], a2);                                   \
          }                                                              \
          ua[o] = tanh_fast(a0); ub[o] = tanh_fast(a1);                  \
          uc[o] = tanh_fast(a2);                                         \
      }                                                                  \
      _Pragma("unroll")                                                  \
      for (int o = 0; o < COUT; ++o) {                                   \
          float a0 = bl[o], a1 = bl[o], a2 = bl[o];                      \
          _Pragma("unroll")                                              \
          for (int c = 0; c < COUT; ++c) {                               \
              float w = wl[o * COUT + c];                                \
              a0 = fmaf(w, ua[c], a0);                                   \
              a1 = fmaf(w, ub[c], a1);                                   \
              a2 = fmaf(w, uc[c], a2);                                   \
          }                                                              \
          a0 *= 10.f; a1 *= 10.f; a2 *= 10.f;                            \
          va[o] = a0; vb[o] = a1; vc[o] = a2;                            \
          s += fabsf(a0) + fabsf(a1) + fabsf(a2);                        \
      } }

#define FIN_PIXEL(vk, kk)                                                \
    { int p = tid + (kk) * NTHREADS; int b = p / HW; int hw = p - b * HW;\
      float* ob = out + (size_t)b * (COUT * HW) + hw;                    \
      _Pragma("unroll")                                                  \
      for (int o = 0; o < COUT; ++o) {                                   \
          float a = bs[o];                                               \
          _Pragma("unroll")                                              \
          for (int c = 0; c < COUT; ++c)                                 \
              a = fmaf(ws[o * COUT + c], vk[c], a);                      \
          ob[(size_t)o * HW] = a;                                        \
      } }

__global__ __launch_bounds__(TPB, BPC) void k_persist(
        const float* __restrict__ x,
        const float* __restrict__ wp, const float* __restrict__ bp,
        const float* __restrict__ wl, const float* __restrict__ bl,
        const float* __restrict__ ws, const float* __restrict__ bs,
        float* __restrict__ out, Ctl* __restrict__ ctl) {
    __shared__ int sense_sh;
    __shared__ float bcast;
    const int t = threadIdx.x;
    if (t == 0) sense_sh = 0;
    __syncthreads();

    const int tid = blockIdx.x * TPB + t;

    // State: 9 named 16-wide vectors = 144 registers. No runtime indexing.
    vfloat16 v0, v1, v2, v3, v4, v5, v6, v7, v8;

    // ---- pre conv + |v| partial
    float s = 0.f;
    PRE_PIXEL(v0, 0) PRE_PIXEL(v1, 1) PRE_PIXEL(v2, 2)
    PRE_PIXEL(v3, 3) PRE_PIXEL(v4, 4) PRE_PIXEL(v5, 5)
    PRE_PIXEL(v6, 6) PRE_PIXEL(v7, 7) PRE_PIXEL(v8, 8)
    {
        float r = block_reduce_add(s);
        if (t == 0)
            __hip_atomic_store(&ctl->partials[0][blockIdx.x], r,
                               __ATOMIC_RELAXED, __HIP_MEMORY_SCOPE_AGENT);
    }
    grid_barrier(ctl, &sense_sh);

    // ---- while (mean|v| < 3): v = 10*(wl @ tanh(ws @ v + bs) + bl)
    int it = 0;
    while (it < MAX_ITERS) {
        float total = grid_sum(ctl->partials[it & 1], &bcast);
        if (total >= 3.0f * NELT) break;      // uniform across all blocks

        s = 0.f;
        STEP_TRIPLE(v0, v1, v2)
        STEP_TRIPLE(v3, v4, v5)
        STEP_TRIPLE(v6, v7, v8)
        ++it;
        float r = block_reduce_add(s);
        if (t == 0)
            __hip_atomic_store(&ctl->partials[it & 1][blockIdx.x], r,
                               __ATOMIC_RELAXED, __HIP_MEMORY_SCOPE_AGENT);
        grid_barrier(ctl, &sense_sh);
    }

    // ---- final conv (per pixel; weights K$-resident)
    FIN_PIXEL(v0, 0) FIN_PIXEL(v1, 1) FIN_PIXEL(v2, 2)
    FIN_PIXEL(v3, 3) FIN_PIXEL(v4, 4) FIN_PIXEL(v5, 5)
    FIN_PIXEL(v6, 6) FIN_PIXEL(v7, 7) FIN_PIXEL(v8, 8)
}

extern "C" void kernel_launch(void* const* d_in, const int* in_sizes, int n_in,
                              void* d_out, int out_size, void* d_ws, size_t ws_size,
                              hipStream_t stream) {
    // dict order: x, w_pre, b_pre, w_loop, b_loop, w_shared, b_shared
    const float* x  = (const float*)d_in[0];
    const float* wp = (const float*)d_in[1];
    const float* bp = (const float*)d_in[2];
    const float* wl = (const float*)d_in[3];
    const float* bl = (const float*)d_in[4];
    const float* ws = (const float*)d_in[5];
    const float* bs = (const float*)d_in[6];
    float* out = (float*)d_out;
    Ctl*   ctl = (Ctl*)d_ws;

    k_init<<<1, 64, 0, stream>>>(ctl);
    k_persist<<<NBLK, TPB, 0, stream>>>(x, wp, bp, wl, bl, ws, bs, out, ctl);
}